// Round 8
// baseline (381.838 us; speedup 1.0000x reference)
//
#include <hip/hip_runtime.h>

// GeomGCN single-channel:
//   1. Bpack = fragment-ordered split-bf16 of W    (wpack, 128 KB)
//   2. fhi/flo = split-bf16 of feat[n]*norm[n]     (featsplit, streaming)
//   3. t[n][c] = bf16((feat[n]*norm[n])·W[c,:])    (MFMA GEMM, B-in-registers,
//      persistent blocks, operand-swapped mfma -> packed row-major stores)
//   4. two-level counting sort of edges by (dst, div):
//        A: bucket histogram (bucket = dst>>8)      -> bcnt
//        B: 1-block scan                            -> bbase, bfront
//        C: block-local multisplit, packed u32 rec  -> rec[] (bucket-ordered)
//        D: per-bucket 1024-bin sort in LDS         -> payload[] (src),
//                                                      cursor4[4N] (ends)
//   5. per-node wave aggregation, predication-free per-div segments
// Constants: N=100000, E=1600000, IN=128, OUT=64, D=4 (D*OUT=256).

#define IN_F   128
#define OUTC   256
#define EPC    4096
#define NBMAX  512
#define STGF   5120
#define GEMM_GRID 512

typedef __bf16 bf16x8 __attribute__((ext_vector_type(8)));
typedef float  f32x4  __attribute__((ext_vector_type(4)));

__device__ inline float bf16_to_f32(unsigned short h) {
    return __uint_as_float(((unsigned int)h) << 16);
}

// ---------------------------------------------------------------------------
// wpack: W [256][128] f32 -> Bpack fragment-ordered split-bf16.
// ---------------------------------------------------------------------------
__global__ __launch_bounds__(256) void wpack_kernel(
    const float* __restrict__ W, bf16x8* __restrict__ Bpack)
{
    const int idx  = blockIdx.x * 256 + threadIdx.x;   // 0..4095 = (s,c,lane)
    const int lane = idx & 63;
    const int c    = (idx >> 6) & 15;
    const int s    = idx >> 10;
    const int col  = c * 16 + (lane & 15);
    const int k0   = s * 32 + (lane >> 4) * 8;
    const float* p = W + col * IN_F + k0;
    bf16x8 h, l;
    #pragma unroll
    for (int e = 0; e < 8; ++e) {
        const float v = p[e];
        const __bf16 hb = (__bf16)v;
        h[e] = hb;
        l[e] = (__bf16)(v - (float)hb);
    }
    Bpack[idx]        = h;
    Bpack[4096 + idx] = l;
}

// ---------------------------------------------------------------------------
// featsplit: g = feat[n]*norm[n]; fhi/flo = split-bf16(g). float4 per thread.
// ---------------------------------------------------------------------------
__global__ __launch_bounds__(256) void featsplit_kernel(
    const float* __restrict__ feat, const float* __restrict__ norm,
    __bf16* __restrict__ fhi, __bf16* __restrict__ flo, int total4)
{
    int i = blockIdx.x * 256 + threadIdx.x;
    if (i >= total4) return;
    const int row = i >> 5;                      // 32 float4 per row
    const float nm = norm[row];
    const float4 v = ((const float4*)feat)[i];
    const float x[4] = {v.x * nm, v.y * nm, v.z * nm, v.w * nm};
    union { __bf16 b[4]; uint2 u; } hi, lo;
    #pragma unroll
    for (int j = 0; j < 4; ++j) {
        const __bf16 hb = (__bf16)x[j];
        hi.b[j] = hb;
        lo.b[j] = (__bf16)(x[j] - (float)hb);
    }
    ((uint2*)fhi)[i] = hi.u;
    ((uint2*)flo)[i] = lo.u;
}

// ---------------------------------------------------------------------------
// MFMA GEMM: 512 persistent blocks x 4 waves; wave owns a 64-col slice with
// B hi/lo resident in 128 VGPRs. A loaded pre-split (no VALU split chain).
// mfma(B,A): lane holds 4 consecutive cols of one row -> packed 8B stores.
// ---------------------------------------------------------------------------
__global__ __launch_bounds__(256, 2) void gemm_mfma_kernel(
    const __bf16* __restrict__ fhi, const __bf16* __restrict__ flo,
    const bf16x8* __restrict__ Bpack, __bf16* __restrict__ t,
    int nNodes, int nTiles)
{
    const int tid  = threadIdx.x;
    const int wid  = tid >> 6;
    const int lane = tid & 63;
    const int r    = lane & 15;
    const int g    = lane >> 4;
    const int c0   = wid << 2;

    bf16x8 bfh[4][4], bfl[4][4];
    #pragma unroll
    for (int s = 0; s < 4; ++s)
        #pragma unroll
        for (int cc = 0; cc < 4; ++cc) {
            bfh[s][cc] = Bpack[(s * 16 + c0 + cc) * 64 + lane];
            bfl[s][cc] = Bpack[4096 + (s * 16 + c0 + cc) * 64 + lane];
        }

    for (int tile = blockIdx.x; tile < nTiles; tile += gridDim.x) {
        const int row0 = tile * 32;
        const int ra0 = min(row0 + r, nNodes - 1);
        const int ra1 = min(row0 + 16 + r, nNodes - 1);
        const __bf16* ph0 = fhi + (size_t)ra0 * IN_F;
        const __bf16* pl0 = flo + (size_t)ra0 * IN_F;
        const __bf16* ph1 = fhi + (size_t)ra1 * IN_F;
        const __bf16* pl1 = flo + (size_t)ra1 * IN_F;

        f32x4 acc[2][4];
        #pragma unroll
        for (int h = 0; h < 2; ++h)
            #pragma unroll
            for (int cc = 0; cc < 4; ++cc)
                acc[h][cc] = (f32x4){0.f, 0.f, 0.f, 0.f};

        #pragma unroll
        for (int s = 0; s < 4; ++s) {
            const int koff = s * 32 + g * 8;
            const bf16x8 a0h = *(const bf16x8*)(ph0 + koff);
            const bf16x8 a0l = *(const bf16x8*)(pl0 + koff);
            const bf16x8 a1h = *(const bf16x8*)(ph1 + koff);
            const bf16x8 a1l = *(const bf16x8*)(pl1 + koff);
            #pragma unroll
            for (int cc = 0; cc < 4; ++cc) {
                acc[0][cc] = __builtin_amdgcn_mfma_f32_16x16x32_bf16(bfh[s][cc], a0h, acc[0][cc], 0, 0, 0);
                acc[0][cc] = __builtin_amdgcn_mfma_f32_16x16x32_bf16(bfh[s][cc], a0l, acc[0][cc], 0, 0, 0);
                acc[0][cc] = __builtin_amdgcn_mfma_f32_16x16x32_bf16(bfl[s][cc], a0h, acc[0][cc], 0, 0, 0);
                acc[1][cc] = __builtin_amdgcn_mfma_f32_16x16x32_bf16(bfh[s][cc], a1h, acc[1][cc], 0, 0, 0);
                acc[1][cc] = __builtin_amdgcn_mfma_f32_16x16x32_bf16(bfh[s][cc], a1l, acc[1][cc], 0, 0, 0);
                acc[1][cc] = __builtin_amdgcn_mfma_f32_16x16x32_bf16(bfl[s][cc], a1h, acc[1][cc], 0, 0, 0);
            }
        }

        #pragma unroll
        for (int h = 0; h < 2; ++h) {
            const int grow = row0 + (h << 4) + r;
            if (grow >= nNodes) continue;
            __bf16* po = t + (size_t)grow * OUTC;
            #pragma unroll
            for (int cc = 0; cc < 4; ++cc) {
                union { __bf16 b[4]; uint2 u; } pk;
                #pragma unroll
                for (int q = 0; q < 4; ++q)
                    pk.b[q] = (__bf16)acc[h][cc][q];
                *(uint2*)(po + (c0 + cc) * 16 + (g << 2)) = pk.u;
            }
        }
    }
}

// ---------------------------------------------------------------------------
// Pass A: bucket histogram, LDS-aggregated.
// ---------------------------------------------------------------------------
__global__ __launch_bounds__(256) void bucket_hist_kernel(
    const int* __restrict__ dst, int* __restrict__ bcnt, int nEdges, int nBuck)
{
    __shared__ int h[NBMAX];
    const int tid = threadIdx.x;
    for (int b = tid; b < nBuck; b += 256) h[b] = 0;
    __syncthreads();
    const int e0 = blockIdx.x * EPC;
    const int cnt = min(EPC, nEdges - e0);
    for (int i = tid; i < cnt; i += 256)
        atomicAdd(&h[((unsigned)dst[e0 + i]) >> 8], 1);
    __syncthreads();
    for (int b = tid; b < nBuck; b += 256)
        if (h[b]) atomicAdd(&bcnt[b], h[b]);
}

// ---------------------------------------------------------------------------
// Pass B: 1-block exclusive scan of bcnt -> bbase, bfront.
// ---------------------------------------------------------------------------
__global__ __launch_bounds__(256) void bucket_scan_kernel(
    const int* __restrict__ bcnt, int* __restrict__ bbase,
    int* __restrict__ bfront, int nBuck)
{
    __shared__ int wsum[4], woff[4];
    const int tid = threadIdx.x;
    const int i0 = 2 * tid, i1 = 2 * tid + 1;
    const int h0 = (i0 < nBuck) ? bcnt[i0] : 0;
    const int h1 = (i1 < nBuck) ? bcnt[i1] : 0;
    const int s = h0 + h1;
    int incl = s;
    const int lane = tid & 63;
    #pragma unroll
    for (int off = 1; off < 64; off <<= 1) {
        const int o = __shfl_up(incl, off);
        if (lane >= off) incl += o;
    }
    if (lane == 63) wsum[tid >> 6] = incl;
    __syncthreads();
    if (tid == 0) { int r = 0; for (int i = 0; i < 4; ++i) { woff[i] = r; r += wsum[i]; } }
    __syncthreads();
    const int e = incl - s + woff[tid >> 6];
    if (i0 < nBuck) { bbase[i0] = e;      bfront[i0] = e;      }
    if (i1 < nBuck) { bbase[i1] = e + h0; bfront[i1] = e + h0; }
}

// ---------------------------------------------------------------------------
// Pass C: block-local multisplit -> bucket-ordered packed rec[] runs.
// rec = (src<<10) | (localnode<<2) | div   (17+8+2 = 27 bits)
// ---------------------------------------------------------------------------
__global__ __launch_bounds__(256) void bucket_place_kernel(
    const int* __restrict__ src, const int* __restrict__ dst,
    const int* __restrict__ ediv, int* __restrict__ bfront,
    unsigned int* __restrict__ rec, int nEdges, int nBuck)
{
    __shared__ unsigned int stg[EPC];          // 16 KB
    __shared__ unsigned short stgB[EPC];       // 8 KB
    __shared__ int hist[NBMAX], excl[NBMAX], cur[NBMAX], gpos[NBMAX];
    __shared__ int wsum[4], woff[4];

    const int tid = threadIdx.x;
    const int e0 = blockIdx.x * EPC;
    const int cnt = min(EPC, nEdges - e0);

    for (int b = tid; b < nBuck; b += 256) hist[b] = 0;
    __syncthreads();

    for (int i = tid; i < cnt; i += 256)
        atomicAdd(&hist[((unsigned)dst[e0 + i]) >> 8], 1);
    __syncthreads();

    {
        const int i0 = 2 * tid, i1 = 2 * tid + 1;
        const int h0 = (i0 < nBuck) ? hist[i0] : 0;
        const int h1 = (i1 < nBuck) ? hist[i1] : 0;
        const int s = h0 + h1;
        int incl = s;
        const int lane = tid & 63;
        #pragma unroll
        for (int off = 1; off < 64; off <<= 1) {
            const int o = __shfl_up(incl, off);
            if (lane >= off) incl += o;
        }
        if (lane == 63) wsum[tid >> 6] = incl;
        __syncthreads();
        if (tid == 0) { int r = 0; for (int i = 0; i < 4; ++i) { woff[i] = r; r += wsum[i]; } }
        __syncthreads();
        const int e = incl - s + woff[tid >> 6];
        if (i0 < nBuck) { excl[i0] = e;      cur[i0] = e;
                          gpos[i0] = h0 ? atomicAdd(&bfront[i0], h0) : 0; }
        if (i1 < nBuck) { excl[i1] = e + h0; cur[i1] = e + h0;
                          gpos[i1] = h1 ? atomicAdd(&bfront[i1], h1) : 0; }
    }
    __syncthreads();

    for (int i = tid; i < cnt; i += 256) {
        const int e = e0 + i;
        const unsigned d = (unsigned)dst[e];
        const int b = d >> 8;
        const int lp = atomicAdd(&cur[b], 1);
        stg[lp]  = ((unsigned)src[e] << 10) | ((d & 255u) << 2) | (unsigned)ediv[e];
        stgB[lp] = (unsigned short)b;
    }
    __syncthreads();

    for (int s2 = tid; s2 < cnt; s2 += 256) {
        const int b = stgB[s2];
        rec[gpos[b] + (s2 - excl[b])] = stg[s2];
    }
}

// ---------------------------------------------------------------------------
// Pass D: per-bucket 1024-bin ((localnode<<2)|div) counting sort in LDS.
// Writes payload[] = src (bucket-segment coalesced) and cursor4[4N] = global
// END offset of each (node,div) segment.
// ---------------------------------------------------------------------------
__global__ __launch_bounds__(256) void bucket_fine_kernel(
    const unsigned int* __restrict__ rec, const int* __restrict__ bbase,
    const int* __restrict__ bcnt, int* __restrict__ cursor4,
    int* __restrict__ payload, int nNodes)
{
    __shared__ int nhist[1024], ncur[1024];    // 8 KB
    __shared__ int pay[STGF];                  // 20 KB
    __shared__ int wsum[4], woff[4];

    const int tid = threadIdx.x;
    const int b = blockIdx.x;
    const int base = bbase[b];
    const int cnt = bcnt[b];
    const int bin0 = b << 10;                  // global bin = node*4+div base
    const int nBins = nNodes * 4;

    #pragma unroll
    for (int j = 0; j < 4; ++j) nhist[tid + j * 256] = 0;
    __syncthreads();
    for (int i = tid; i < cnt; i += 256)
        atomicAdd(&nhist[rec[base + i] & 1023u], 1);
    __syncthreads();

    // scan 1024 bins: thread owns 4 consecutive
    const int4 h4 = *(const int4*)&nhist[tid << 2];
    const int s = h4.x + h4.y + h4.z + h4.w;
    int incl = s;
    const int lane = tid & 63;
    #pragma unroll
    for (int off = 1; off < 64; off <<= 1) {
        const int o = __shfl_up(incl, off);
        if (lane >= off) incl += o;
    }
    if (lane == 63) wsum[tid >> 6] = incl;
    __syncthreads();
    if (tid == 0) { int r = 0; for (int i = 0; i < 4; ++i) { woff[i] = r; r += wsum[i]; } }
    __syncthreads();
    const int ebase = incl - s + woff[tid >> 6];   // exclusive start of bin 4*tid
    const int p1 = ebase + h4.x;
    const int p2 = p1 + h4.y;
    const int p3 = p2 + h4.z;
    const int p4 = p3 + h4.w;
    ncur[(tid << 2) + 0] = ebase;
    ncur[(tid << 2) + 1] = p1;
    ncur[(tid << 2) + 2] = p2;
    ncur[(tid << 2) + 3] = p3;
    {   // global END offsets
        const int gb = bin0 + (tid << 2);
        if (gb + 0 < nBins) cursor4[gb + 0] = base + p1;
        if (gb + 1 < nBins) cursor4[gb + 1] = base + p2;
        if (gb + 2 < nBins) cursor4[gb + 2] = base + p3;
        if (gb + 3 < nBins) cursor4[gb + 3] = base + p4;
    }
    __syncthreads();

    if (cnt <= STGF) {
        for (int i = tid; i < cnt; i += 256) {
            const unsigned int rr = rec[base + i];
            pay[atomicAdd(&ncur[rr & 1023u], 1)] = (int)(rr >> 10);
        }
        __syncthreads();
        for (int i = tid; i < cnt; i += 256) payload[base + i] = pay[i];
    } else {
        for (int i = tid; i < cnt; i += 256) {
            const unsigned int rr = rec[base + i];
            payload[base + atomicAdd(&ncur[rr & 1023u], 1)] = (int)(rr >> 10);
        }
    }
}

// ---------------------------------------------------------------------------
// Aggregation: one wave per node; lane = feature; 4 predication-free
// per-div segment loops driven by cursor4.
// ---------------------------------------------------------------------------
__device__ inline float seg_sum(const unsigned short* __restrict__ tp,
                                const int* __restrict__ payload,
                                int& e, const int end)
{
    float a = 0.f, b = 0.f;
    for (; e + 1 < end; e += 2) {
        const int s0 = payload[e];
        const int s1 = payload[e + 1];
        a += bf16_to_f32(tp[(size_t)s0 << 8]);
        b += bf16_to_f32(tp[(size_t)s1 << 8]);
    }
    if (e < end) { a += bf16_to_f32(tp[(size_t)payload[e] << 8]); ++e; }
    return a + b;
}

__global__ __launch_bounds__(256) void aggregate_kernel(
    const unsigned short* __restrict__ t, const int* __restrict__ cursor4,
    const int* __restrict__ payload, const float* __restrict__ norm,
    float* __restrict__ out, int nNodes)
{
    const int wave = (int)((blockIdx.x * 256u + threadIdx.x) >> 6);
    const int lane = threadIdx.x & 63;
    if (wave >= nNodes) return;
    const int idx4 = wave << 2;
    const int4 ends = *(const int4*)(cursor4 + idx4);
    int e = idx4 ? cursor4[idx4 - 1] : 0;

    const float a0 = seg_sum(t + lane,       payload, e, ends.x);
    const float a1 = seg_sum(t + 64 + lane,  payload, e, ends.y);
    const float a2 = seg_sum(t + 128 + lane, payload, e, ends.z);
    const float a3 = seg_sum(t + 192 + lane, payload, e, ends.w);

    const float nm = norm[wave];
    float* po = out + (size_t)wave * OUTC;
    po[0 * 64 + lane] = fmaxf(a0 * nm, 0.f);
    po[1 * 64 + lane] = fmaxf(a1 * nm, 0.f);
    po[2 * 64 + lane] = fmaxf(a2 * nm, 0.f);
    po[3 * 64 + lane] = fmaxf(a3 * nm, 0.f);
}

// ===========================================================================
extern "C" void kernel_launch(void* const* d_in, const int* in_sizes, int n_in,
                              void* d_out, int out_size, void* d_ws, size_t ws_size,
                              hipStream_t stream) {
    const float* feat = (const float*)d_in[0];   // [N,128]
    const float* W    = (const float*)d_in[1];   // [4,64,128] == [256][128]
    const float* norm = (const float*)d_in[2];   // [N,1]
    const int*   src  = (const int*)d_in[3];     // [E]
    const int*   dst  = (const int*)d_in[4];     // [E]
    const int*   ediv = (const int*)d_in[5];     // [E]
    float* out = (float*)d_out;                  // [N,256]

    const int nNodes = in_sizes[0] / IN_F;
    const int nEdges = in_sizes[3];
    const int nBuck  = (nNodes + 255) >> 8;               // 391
    const int nChunk = (nEdges + EPC - 1) / EPC;          // 391
    const int nTiles = (nNodes + 31) / 32;                // 3125

    char* ws = (char*)d_ws;
    const size_t t_bytes  = (size_t)nNodes * OUTC * sizeof(__bf16);  // 51.2 MB
    const size_t f_bytes  = (size_t)nNodes * IN_F * sizeof(__bf16);  // 25.6 MB
    const size_t rec_bytes    = (size_t)nEdges * sizeof(unsigned);   // 6.4 MB
    const size_t pay_bytes    = (size_t)nEdges * sizeof(int);        // 6.4 MB
    const size_t bp_bytes     = 8192 * sizeof(bf16x8);               // 128 KB

    __bf16* t   = (__bf16*)ws;
    char*   r2  = ws + t_bytes;                 // region2: fhi/flo, then sort
    __bf16* fhi = (__bf16*)r2;
    __bf16* flo = (__bf16*)(r2 + f_bytes);
    // after gemm, fhi/flo are dead; sort aliases region2:
    unsigned* rec     = (unsigned*)r2;
    int*      payload = (int*)(r2 + rec_bytes);
    int*      cursor4 = (int*)(r2 + rec_bytes + pay_bytes);
    bf16x8* Bpack = (bf16x8*)(r2 + 2 * f_bytes);
    int*    bcnt  = (int*)(r2 + 2 * f_bytes + bp_bytes);
    int*    bbase  = bcnt + NBMAX;
    int*    bfront = bcnt + 2 * NBMAX;
    (void)ws_size; (void)out_size; (void)n_in;

    hipMemsetAsync(bcnt, 0, nBuck * sizeof(int), stream);
    wpack_kernel<<<16, 256, 0, stream>>>(W, Bpack);
    const int total4 = nNodes * (IN_F / 4);
    featsplit_kernel<<<(total4 + 255) / 256, 256, 0, stream>>>(feat, norm, fhi, flo,
                                                               total4);
    gemm_mfma_kernel<<<GEMM_GRID, 256, 0, stream>>>(fhi, flo, Bpack, t,
                                                    nNodes, nTiles);
    bucket_hist_kernel<<<nChunk, 256, 0, stream>>>(dst, bcnt, nEdges, nBuck);
    bucket_scan_kernel<<<1, 256, 0, stream>>>(bcnt, bbase, bfront, nBuck);
    bucket_place_kernel<<<nChunk, 256, 0, stream>>>(src, dst, ediv, bfront, rec,
                                                    nEdges, nBuck);
    bucket_fine_kernel<<<nBuck, 256, 0, stream>>>(rec, bbase, bcnt, cursor4, payload,
                                                  nNodes);
    aggregate_kernel<<<(nNodes + 3) / 4, 256, 0, stream>>>((const unsigned short*)t,
                                                           cursor4, payload, norm,
                                                           out, nNodes);
}